// Round 2
// baseline (1228.156 us; speedup 1.0000x reference)
//
#include <hip/hip_runtime.h>
#include <stdint.h>

#define TOKENS 2048
#define H_DIM 3584
#define I_DIM 18944

typedef int v4i __attribute__((ext_vector_type(4)));

__device__ __forceinline__ void async_copy16(const void* g, void* lds) {
    __builtin_amdgcn_global_load_lds(
        (const __attribute__((address_space(1))) void*)g,
        (__attribute__((address_space(3))) void*)lds,
        16, 0, 0);
}

// BK=64 LDS swizzle: rows are 64 B = 4 slots of 16 B. Physical slot s of
// row r holds global k-chunk s ^ sigma(r), sigma(r) = (r>>1)&3.
// Staging thread t (row t>>2 + 64j/128j, slot t&3) fetches global chunk
// (t&3)^((t>>3)&3) — j-invariant since 64,128 are multiples of 8 rows.
// Reader of (row, logical chunk fq) uses slot fq^((fr>>1)&3) (row ≡ fr mod
// 16-row fragments; 16-row strides don't change sigma). 64 lanes spread
// uniformly 8-per-4-bank-group with distinct rows — same uniformity class
// as the round-1 BK=128 pattern (measured SQ_LDS_BANK_CONFLICT = 0).

// ---------------------------------------------------------------------------
// Kernel 0: pack the three int32-materialized int8 weights, 16 outputs/thread
// ---------------------------------------------------------------------------
__global__ __launch_bounds__(256)
void pack3_kernel(const int* __restrict__ s0, int8_t* __restrict__ d0,
                  const int* __restrict__ s1, int8_t* __restrict__ d1,
                  const int* __restrict__ s2, int8_t* __restrict__ d2,
                  int pb) {
    int b = blockIdx.x;
    const int* src; int8_t* dst;
    if (b >= 2 * pb)    { src = s2; dst = d2; b -= 2 * pb; }
    else if (b >= pb)   { src = s1; dst = d1; b -= pb; }
    else                { src = s0; dst = d0; }
    const size_t i = (size_t)b * 256 + threadIdx.x;   // 16B-output index, exact
    const v4i* s = (const v4i*)src + i * 4;
    v4i w0 = s[0], w1 = s[1], w2 = s[2], w3 = s[3];
    v4i p;
    p.x = (w0.x & 0xff) | ((w0.y & 0xff) << 8) | ((w0.z & 0xff) << 16) | (w0.w << 24);
    p.y = (w1.x & 0xff) | ((w1.y & 0xff) << 8) | ((w1.z & 0xff) << 16) | (w1.w << 24);
    p.z = (w2.x & 0xff) | ((w2.y & 0xff) << 8) | ((w2.z & 0xff) << 16) | (w2.w << 24);
    p.w = (w3.x & 0xff) | ((w3.y & 0xff) << 8) | ((w3.z & 0xff) << 16) | (w3.w << 24);
    ((v4i*)dst)[i] = p;
}

// ---------------------------------------------------------------------------
// Kernel 1: per-token dynamic symmetric int8 quant of x [T, H], float4 loads
// ---------------------------------------------------------------------------
__global__ __launch_bounds__(256)
void quant_x_kernel(const float* __restrict__ x,
                    int8_t* __restrict__ qx,
                    float* __restrict__ sx) {
    const int row = blockIdx.x;
    const float4* xr = (const float4*)(x + (size_t)row * H_DIM);   // 896 vecs
    float m = 0.0f;
    for (int j = threadIdx.x; j < 896; j += 256) {
        float4 v = xr[j];
        m = fmaxf(m, fmaxf(fmaxf(fabsf(v.x), fabsf(v.y)),
                           fmaxf(fabsf(v.z), fabsf(v.w))));
    }
    for (int off = 32; off > 0; off >>= 1)
        m = fmaxf(m, __shfl_down(m, off, 64));
    __shared__ float wmax[4];
    if ((threadIdx.x & 63) == 0) wmax[threadIdx.x >> 6] = m;
    __syncthreads();
    float mm = fmaxf(fmaxf(wmax[0], wmax[1]), fmaxf(wmax[2], wmax[3]));
    float s = fmaxf(mm / 127.0f, 1e-8f);
    if (threadIdx.x == 0) sx[row] = s;
    int* qrow = (int*)(qx + (size_t)row * H_DIM);
    for (int j = threadIdx.x; j < 896; j += 256) {
        float4 v = xr[j];
        int q0 = (int)fminf(fmaxf(rintf(v.x / s), -127.0f), 127.0f);
        int q1 = (int)fminf(fmaxf(rintf(v.y / s), -127.0f), 127.0f);
        int q2 = (int)fminf(fmaxf(rintf(v.z / s), -127.0f), 127.0f);
        int q3 = (int)fminf(fmaxf(rintf(v.w / s), -127.0f), 127.0f);
        qrow[j] = (q0 & 0xff) | ((q1 & 0xff) << 8) | ((q2 & 0xff) << 16) |
                  (q3 << 24);
    }
}

// ---------------------------------------------------------------------------
// Kernel 2: fused fc1 — gate & up int8 GEMM + SwiGLU + static requant
//   BM=256, BN=128 I-cols, ring of 4 BK=64 slots (128 KiB LDS), 512 thr /
//   8 waves (2M x 4N), wave tile 128 x 32 I-cols x {G,U}. 2 phases/quantum,
//   16 MFMA each. Prefetch 3 quanta ahead; counted s_waitcnt vmcnt(8)
//   (never 0 in steady state). 4 gload_lds per thread per quantum.
// ---------------------------------------------------------------------------
#define FC1_STAGE_A(PS, KQ) do {                                               \
    int8_t* _lA = &lds[PS][0] + tid * 16;                                      \
    async_copy16(gA + (size_t)(KQ) * 64,                      _lA);            \
    async_copy16(gA + (size_t)(KQ) * 64 + 128 * H_DIM,        _lA + 8192);     \
  } while (0)

#define FC1_STAGE_B(PS, KQ) do {                                               \
    int8_t* _lB = &lds[PS][16384] + tid * 16;                                  \
    async_copy16(gG + (size_t)(KQ) * 64, _lB);                                 \
    async_copy16(gU + (size_t)(KQ) * 64, _lB + 8192);                          \
  } while (0)

#define FC1_READ_A(MH) do { _Pragma("unroll")                                  \
  for (int m_ = 0; m_ < 4; ++m_)                                               \
    a[m_] = *(const v4i*)(Ab + aOff + (MH) * 4096 + m_ * 1024);                \
  } while (0)

#define FC1_READ_B() do { _Pragma("unroll")                                    \
  for (int n_ = 0; n_ < 2; ++n_) {                                             \
    bg[n_] = *(const v4i*)(Bb + bOff + n_ * 1024);                             \
    bu[n_] = *(const v4i*)(Bb + bOff + 8192 + n_ * 1024);                      \
  } } while (0)

#define FC1_MFMA16(MH) do { _Pragma("unroll")                                  \
  for (int m_ = 0; m_ < 4; ++m_) { _Pragma("unroll")                           \
    for (int n_ = 0; n_ < 2; ++n_) {                                           \
      accG[(MH)*4+m_][n_] = __builtin_amdgcn_mfma_i32_16x16x64_i8(             \
          a[m_], bg[n_], accG[(MH)*4+m_][n_], 0, 0, 0);                        \
      accU[(MH)*4+m_][n_] = __builtin_amdgcn_mfma_i32_16x16x64_i8(             \
          a[m_], bu[n_], accU[(MH)*4+m_][n_], 0, 0, 0);                        \
    } } } while (0)

__global__ __launch_bounds__(512, 2)
void fc1_kernel(const int8_t* __restrict__ qx,
                const float* __restrict__ sx,
                const int8_t* __restrict__ gw,
                const int8_t* __restrict__ uw,
                const float* __restrict__ gws,
                const float* __restrict__ uws,
                const float* __restrict__ dis,
                int8_t* __restrict__ qh) {
    __shared__ __align__(16) int8_t lds[4][32768];   // slot: A 16K | B(G|U) 16K

    const int tid  = threadIdx.x;
    const int wave = tid >> 6;
    const int lane = tid & 63;
    const int wr = wave >> 2;          // 0..1  -> 128-row half
    const int wc = wave & 3;           // 0..3  -> 32 I-cols
    const int fr = lane & 15;
    const int fq = lane >> 4;

    // XCD swizzle: 1184 blocks = 8 chunks of 148, m (8) fastest in chunk
    const int bid = blockIdx.x;
    const int gid = (bid & 7) * 148 + (bid >> 3);
    const int m0 = (gid & 7) * 256;
    const int n0 = (gid >> 3) * 128;

    const int rowS  = tid >> 2;                          // 0..127
    const int kOffS = ((tid & 3) ^ ((tid >> 3) & 3)) * 16;
    const int8_t* gA = qx + (size_t)(m0 + rowS) * H_DIM + kOffS;
    const int8_t* gG = gw + (size_t)(n0 + rowS) * H_DIM + kOffS;
    const int8_t* gU = uw + (size_t)(n0 + rowS) * H_DIM + kOffS;

    const int swz  = (fq ^ ((fr >> 1) & 3)) * 16;
    const int aOff = wr * 8192 + fr * 64 + swz;          // + m*1024
    const int bOff = wc * 2048 + fr * 64 + swz;          // + n*1024 (U at +8192)

    v4i accG[8][2] = {};
    v4i accU[8][2] = {};
    v4i a[4], bg[2], bu[2];

    const int NT = H_DIM / 64;                            // 56
    // prologue: stage quanta 0,1,2 (12 loads in flight)
    FC1_STAGE_A(0, 0); FC1_STAGE_B(0, 0);
    FC1_STAGE_A(1, 1); FC1_STAGE_B(1, 1);
    FC1_STAGE_A(2, 2); FC1_STAGE_B(2, 2);
    __builtin_amdgcn_sched_barrier(0);
    asm volatile("s_waitcnt vmcnt(8)" ::: "memory");      // quantum 0 landed
    __builtin_amdgcn_s_barrier();
    __builtin_amdgcn_sched_barrier(0);

    for (int q = 0; q < NT; ++q) {
        const int rs = q & 3;
        const int ps = (q + 3) & 3;
        const bool pf = (q + 3) < NT;
        const int8_t* Ab = &lds[rs][0];
        const int8_t* Bb = &lds[rs][16384];

        // ---- phase A: stage next-A, read A(0..3)+all B, 16 MFMA
        if (pf) FC1_STAGE_A(ps, q + 3);
        FC1_READ_A(0);
        FC1_READ_B();
        __builtin_amdgcn_s_barrier();
        __builtin_amdgcn_s_setprio(1);
        FC1_MFMA16(0);
        __builtin_amdgcn_s_setprio(0);
        __builtin_amdgcn_s_barrier();
        __builtin_amdgcn_sched_barrier(0);

        // ---- phase B: stage next-B, read A(4..7), 16 MFMA
        if (pf) FC1_STAGE_B(ps, q + 3);
        FC1_READ_A(1);
        __builtin_amdgcn_s_barrier();
        __builtin_amdgcn_s_setprio(1);
        FC1_MFMA16(1);
        __builtin_amdgcn_s_setprio(0);
        __builtin_amdgcn_sched_barrier(0);
        // counted drain: quantum q+1's loads (oldest 4) must have landed
        if (q < NT - 3)       asm volatile("s_waitcnt vmcnt(8)" ::: "memory");
        else if (q == NT - 3) asm volatile("s_waitcnt vmcnt(4)" ::: "memory");
        else if (q == NT - 2) asm volatile("s_waitcnt vmcnt(0)" ::: "memory");
        if (q < NT - 1) {
            __builtin_amdgcn_s_barrier();
            __builtin_amdgcn_sched_barrier(0);
        }
    }

    const float gscale = *gws;
    const float uscale = *uws;
    const float dis_v  = *dis;

    // C/D layout: row = (lane>>4)*4 + r, col = lane&15
#pragma unroll
    for (int M = 0; M < 8; ++M) {
#pragma unroll
        for (int r = 0; r < 4; ++r) {
            const int row = m0 + wr * 128 + M * 16 + fq * 4 + r;
            const float s  = sx[row];
            const float gs = s * gscale;
            const float us = s * uscale;
            const size_t base = (size_t)row * I_DIM + n0 + wc * 32;
#pragma unroll
            for (int nf = 0; nf < 2; ++nf) {
                float g = (float)accG[M][nf][r] * gs;
                float u = (float)accU[M][nf][r] * us;
                float h = (g / (1.0f + expf(-g))) * u;   // silu(g) * u
                float q = rintf(h / dis_v);
                q = fminf(fmaxf(q, -127.0f), 127.0f);
                qh[base + nf * 16 + fr] = (int8_t)q;
            }
        }
    }
}

// ---------------------------------------------------------------------------
// Kernel 3: fc2 — qh [T, I] x down_w [H, I] -> out [T, H] fp32
//   BM=128, BN=128, ring of 4 BK=64 slots (64 KiB -> 2 blocks/CU), 256 thr /
//   4 waves (2x2), wave tile 64x64. 1 phase/quantum (16 MFMA), prefetch 3
//   ahead, counted vmcnt(8).
// ---------------------------------------------------------------------------
#define FC2_STAGE(PS, KQ) do {                                                 \
    int8_t* _lA = &lds[PS][0]    + tid * 16;                                   \
    int8_t* _lB = &lds[PS][8192] + tid * 16;                                   \
    async_copy16(gA + (size_t)(KQ) * 64,                  _lA);                \
    async_copy16(gA + (size_t)(KQ) * 64 + 64 * I_DIM,     _lA + 4096);         \
    async_copy16(gW + (size_t)(KQ) * 64,                  _lB);                 \
    async_copy16(gW + (size_t)(KQ) * 64 + 64 * I_DIM,     _lB + 4096);         \
  } while (0)

#define FC2_READ() do { _Pragma("unroll")                                      \
  for (int m_ = 0; m_ < 4; ++m_)                                               \
    a[m_] = *(const v4i*)(Ab + aOff + m_ * 1024);                              \
  _Pragma("unroll")                                                            \
  for (int n_ = 0; n_ < 4; ++n_)                                               \
    b[n_] = *(const v4i*)(Ab + bOff + n_ * 1024);                              \
  } while (0)

#define FC2_MFMA16() do { _Pragma("unroll")                                    \
  for (int m_ = 0; m_ < 4; ++m_) { _Pragma("unroll")                           \
    for (int n_ = 0; n_ < 4; ++n_)                                             \
      acc[m_][n_] = __builtin_amdgcn_mfma_i32_16x16x64_i8(                     \
          a[m_], b[n_], acc[m_][n_], 0, 0, 0);                                 \
  } } while (0)

__global__ __launch_bounds__(256, 2)
void fc2_kernel(const int8_t* __restrict__ qh,
                const int8_t* __restrict__ dw,
                const float* __restrict__ dws,
                const float* __restrict__ dis,
                float* __restrict__ out) {
    __shared__ __align__(16) int8_t lds[4][16384];   // slot: A 8K | B 8K

    const int tid  = threadIdx.x;
    const int wave = tid >> 6;
    const int lane = tid & 63;
    const int wr = wave >> 1;          // 0..1
    const int wc = wave & 1;           // 0..1
    const int fr = lane & 15;
    const int fq = lane >> 4;

    // XCD swizzle: 448 blocks = 8 chunks of 56, m (16) fastest in chunk
    const int bid = blockIdx.x;
    const int gid = (bid & 7) * 56 + (bid >> 3);
    const int m0 = (gid & 15) * 128;
    const int n0 = (gid >> 4) * 128;

    const int rowS  = tid >> 2;                          // 0..63
    const int kOffS = ((tid & 3) ^ ((tid >> 3) & 3)) * 16;
    const int8_t* gA = qh + (size_t)(m0 + rowS) * I_DIM + kOffS;
    const int8_t* gW = dw + (size_t)(n0 + rowS) * I_DIM + kOffS;

    const int swz  = (fq ^ ((fr >> 1) & 3)) * 16;
    const int aOff = wr * 4096 + fr * 64 + swz;
    const int bOff = 8192 + wc * 4096 + fr * 64 + swz;

    v4i acc[4][4] = {};
    v4i a[4], b[4];

    const int NT = I_DIM / 64;                            // 296
    FC2_STAGE(0, 0);
    FC2_STAGE(1, 1);
    FC2_STAGE(2, 2);
    __builtin_amdgcn_sched_barrier(0);
    asm volatile("s_waitcnt vmcnt(8)" ::: "memory");
    __builtin_amdgcn_s_barrier();
    __builtin_amdgcn_sched_barrier(0);

    for (int q = 0; q < NT; ++q) {
        const int rs = q & 3;
        const int ps = (q + 3) & 3;
        const bool pf = (q + 3) < NT;
        const int8_t* Ab = &lds[rs][0];

        if (pf) FC2_STAGE(ps, q + 3);
        FC2_READ();
        __builtin_amdgcn_s_barrier();
        __builtin_amdgcn_s_setprio(1);
        FC2_MFMA16();
        __builtin_amdgcn_s_setprio(0);
        __builtin_amdgcn_sched_barrier(0);
        if (q < NT - 3)       asm volatile("s_waitcnt vmcnt(8)" ::: "memory");
        else if (q == NT - 3) asm volatile("s_waitcnt vmcnt(4)" ::: "memory");
        else if (q == NT - 2) asm volatile("s_waitcnt vmcnt(0)" ::: "memory");
        if (q < NT - 1) {
            __builtin_amdgcn_s_barrier();
            __builtin_amdgcn_sched_barrier(0);
        }
    }

    const float sc = (*dis) * (*dws);
#pragma unroll
    for (int m_ = 0; m_ < 4; ++m_)
#pragma unroll
        for (int n_ = 0; n_ < 4; ++n_)
#pragma unroll
            for (int r = 0; r < 4; ++r) {
                const int row = m0 + wr * 64 + m_ * 16 + fq * 4 + r;
                const int col = n0 + wc * 64 + n_ * 16 + fr;
                out[(size_t)row * H_DIM + col] = (float)acc[m_][n_][r] * sc;
            }
}

// ---------------------------------------------------------------------------
extern "C" void kernel_launch(void* const* d_in, const int* in_sizes, int n_in,
                              void* d_out, int out_size, void* d_ws, size_t ws_size,
                              hipStream_t stream) {
    const float* x    = (const float*)d_in[0];
    const int*   gw32 = (const int*)d_in[1];   // integer inputs arrive as int32
    const int*   uw32 = (const int*)d_in[2];
    const int*   dw32 = (const int*)d_in[3];
    const float* gws  = (const float*)d_in[4];
    const float* uws  = (const float*)d_in[5];
    const float* dws  = (const float*)d_in[6];
    const float* dis  = (const float*)d_in[7];
    float* out = (float*)d_out;

    // workspace: qx [T*H] i8 | sx [T] f32 | qh [T*I] i8 | gw8 | uw8 | dw8
    const size_t W = (size_t)I_DIM * H_DIM;
    int8_t* qx  = (int8_t*)d_ws;
    float*  sx  = (float*)((char*)d_ws + (size_t)TOKENS * H_DIM);
    int8_t* qh  = (int8_t*)((char*)d_ws + (size_t)TOKENS * H_DIM + TOKENS * 4);
    int8_t* gw8 = (int8_t*)((char*)d_ws + (size_t)TOKENS * H_DIM + TOKENS * 4
                            + (size_t)TOKENS * I_DIM);
    int8_t* uw8 = gw8 + W;
    int8_t* dw8 = uw8 + W;

    const int pb = (int)(W / 16 / 256);   // 16576 blocks per matrix, exact
    pack3_kernel<<<3 * pb, 256, 0, stream>>>(gw32, gw8, uw32, uw8, dw32, dw8, pb);

    quant_x_kernel<<<TOKENS, 256, 0, stream>>>(x, qx, sx);

    fc1_kernel<<<(TOKENS / 256) * (I_DIM / 128), 512, 0, stream>>>(
        qx, sx, gw8, uw8, gws, uws, dis, qh);

    fc2_kernel<<<(TOKENS / 128) * (H_DIM / 128), 256, 0, stream>>>(
        qh, dw8, dws, dis, out);
}